// Round 8
// baseline (95.574 us; speedup 1.0000x reference)
//
#include <hip/hip_runtime.h>
#include <cstdint>

#define CH 192
#define HW 65536
#define PN 64           // pixels per tile
#define PITCH 196       // dense path: X-tile LDS row pitch (bf16 elems)
#define OPITCH 66       // dense path: out-tile LDS row pitch (fp32 elems)
#define KB 6            // K blocks (192/32)
#define SMEM_BYTES 50688

#define GAMMA_BOUND 3.814697265625e-06f            // 2^-18
#define PEDESTAL    1.4551915228366852e-11f        // 2^-36
#define BETA_BOUND  1.0000072759550125e-03f        // sqrt(1e-6 + 2^-36)

typedef __attribute__((ext_vector_type(8))) __bf16 bf16x8;
typedef __attribute__((ext_vector_type(4))) __bf16 bf16x4;
typedef __attribute__((ext_vector_type(4))) float  f32x4;

__device__ __forceinline__ ushort f2bf(float f) {
    __bf16 h = (__bf16)f;
    return __builtin_bit_cast(ushort, h);
}
__device__ __forceinline__ float bf2f(ushort h) {
    union { uint32_t u; float f; } v; v.u = ((uint32_t)h) << 16;
    return v.f;
}
__device__ __forceinline__ float rsq(float x) {
    float r; asm("v_rsq_f32 %0, %1" : "=v"(r) : "v"(x)); return r;
}

// ---- kernel 0: zero the structure flag (ws not re-poisoned between replays) ----
__global__ void gsdn_flag0(unsigned* flag) { *flag = 0u; }

// ---- prep: reparam params; G2/G1 -> MFMA A-frag order (dense path);
//      diagonal + bias table (diag path); off-diagonal detection -> flag ----
__global__ __launch_bounds__(256) void gsdn_prep(
    const float* __restrict__ beta, const float* __restrict__ gamma,
    const float* __restrict__ beta2, const float* __restrict__ gamma2,
    ushort* __restrict__ g2sw, ushort* __restrict__ g1sw,
    float* __restrict__ b2r, float* __restrict__ b1r,
    float4* __restrict__ cp, unsigned* __restrict__ flag)
{
    int t = blockIdx.x * 256 + threadIdx.x;
    if (t < 12 * KB * 64) {
        const int o    = t / (KB * 64);
        const int r    = t - o * (KB * 64);
        const int kb   = r >> 6;
        const int lane = r & 63;
        const int row  = o * 16 + (lane & 15);
        const int col0 = kb * 32 + 8 * (lane >> 4);
        ushort w2[8], w1[8];
        bool nz = false;
        #pragma unroll
        for (int j = 0; j < 8; ++j) {
            float g = fmaxf(gamma2[row * CH + col0 + j], GAMMA_BOUND);
            float g2v = g * g - PEDESTAL;
            w2[j] = f2bf(g2v);
            float h = fmaxf(gamma[row * CH + col0 + j], GAMMA_BOUND);
            float g1v = h * h - PEDESTAL;
            w1[j] = f2bf(g1v);
            if (row != (col0 + j) && (g2v != 0.0f || g1v != 0.0f)) nz = true;
        }
        #pragma unroll
        for (int j = 0; j < 8; ++j) { g2sw[t * 8 + j] = w2[j]; g1sw[t * 8 + j] = w1[j]; }
        if (nz) atomicOr(flag, 1u);
    }
    if (t < CH) {
        float b = fmaxf(beta2[t], BETA_BOUND);
        float b2 = b * b - PEDESTAL;
        float a = fmaxf(beta[t], BETA_BOUND);
        float b1 = a * a - PEDESTAL;
        b2r[t] = b2;
        b1r[t] = b1;
        float gd = fmaxf(gamma2[t * CH + t], GAMMA_BOUND);
        float d2 = gd * gd - PEDESTAL;
        float hd = fmaxf(gamma[t * CH + t], GAMMA_BOUND);
        float d1 = hd * hd - PEDESTAL;
        float4 p;
        p.x = 1.0f - d2;   // x = p.x*v - b2
        p.y = b2;
        p.z = d1;          // out = x*rsqrt(d1*x^2 + b1)
        p.w = b1;
        cp[t] = p;
    }
}

__device__ __forceinline__ bf16x8 ldsfrag(const ushort* S, int n, int k0) {
    union { bf16x8 v; struct { bf16x4 lo; bf16x4 hi; } s; } u;
    u.s.lo = *(const bf16x4*)&S[n * PITCH + k0];
    u.s.hi = *(const bf16x4*)&S[n * PITCH + k0 + 4];
    return u.v;
}

// ---- fused main: diag (elementwise fp32) or dense (MFMA) per runtime structure flag ----
__global__ __launch_bounds__(256, 3) void gsdn_main(
    const float* __restrict__ X,
    const ushort* __restrict__ g2sw, const ushort* __restrict__ g1sw,
    const float* __restrict__ b2r, const float* __restrict__ b1r,
    const float4* __restrict__ cp, const unsigned* __restrict__ flag,
    float* __restrict__ Y)
{
    const int tid  = threadIdx.x;
    const int base = blockIdx.x * PN;
    const float* Xb = X + (size_t)blockIdx.y * CH * HW + base;
    float*       Yb = Y + (size_t)blockIdx.y * CH * HW + base;

    if (*flag == 0u) {
        // ---- diagonal fast path: pure elementwise fp32 on this WG's tile ----
        #pragma unroll
        for (int i = 0; i < 12; ++i) {
            const int chunk = tid + 256 * i;     // 0..3071 = c*16 + q4
            const int c  = chunk >> 4;
            const int q4 = chunk & 15;
            const float4 p = cp[c];
            const float4 v = *(const float4*)&Xb[(size_t)c * HW + 4 * q4];
            float x0 = p.x * v.x - p.y;
            float x1 = p.x * v.y - p.y;
            float x2 = p.x * v.z - p.y;
            float x3 = p.x * v.w - p.y;
            float4 o;
            o.x = x0 * rsq(p.z * x0 * x0 + p.w);
            o.y = x1 * rsq(p.z * x1 * x1 + p.w);
            o.z = x2 * rsq(p.z * x2 * x2 + p.w);
            o.w = x3 * rsq(p.z * x3 * x3 + p.w);
            *(float4*)&Yb[(size_t)c * HW + 4 * q4] = o;
        }
        return;
    }

    // ---- dense path (r5-verified MFMA kernel) ----
    __shared__ char smem_raw[SMEM_BYTES];
    ushort* Xs = (ushort*)smem_raw;
    float*  Of = (float*)smem_raw;

    const int wave = tid >> 6;
    const int lane = tid & 63;
    const int lm   = lane & 15;
    const int lh   = lane >> 4;

    {
        const int g  = tid & 15;
        const int c0 = tid >> 4;
        #pragma unroll
        for (int j = 0; j < 12; ++j) {
            const int c = c0 + 16 * j;
            const float4 v = *(const float4*)&Xb[(size_t)c * HW + 4 * g];
            Xs[(4 * g + 0) * PITCH + c] = f2bf(v.x);
            Xs[(4 * g + 1) * PITCH + c] = f2bf(v.y);
            Xs[(4 * g + 2) * PITCH + c] = f2bf(v.z);
            Xs[(4 * g + 3) * PITCH + c] = f2bf(v.w);
        }
    }
    __syncthreads();

    f32x4 acc[3][4];
    #pragma unroll
    for (int o = 0; o < 3; ++o)
        #pragma unroll
        for (int nb = 0; nb < 4; ++nb)
            acc[o][nb] = (f32x4){0.f, 0.f, 0.f, 0.f};

    #pragma unroll
    for (int kb = 0; kb < KB; ++kb) {
        bf16x8 bfr[4];
        #pragma unroll
        for (int nb = 0; nb < 4; ++nb)
            bfr[nb] = ldsfrag(Xs, nb * 16 + lm, kb * 32 + 8 * lh);
        #pragma unroll
        for (int o = 0; o < 3; ++o) {
            bf16x8 afr = *(const bf16x8*)(g2sw + (((3 * wave + o) * KB + kb) * 64 + lane) * 8);
            #pragma unroll
            for (int nb = 0; nb < 4; ++nb)
                acc[o][nb] = __builtin_amdgcn_mfma_f32_16x16x32_bf16(afr, bfr[nb], acc[o][nb], 0, 0, 0);
        }
    }
    __syncthreads();

    f32x4 xr[3][4];
    #pragma unroll
    for (int o = 0; o < 3; ++o) {
        const int cb = (3 * wave + o) * 16 + 4 * lh;
        const float4 b2v = *(const float4*)(b2r + cb);
        #pragma unroll
        for (int nb = 0; nb < 4; ++nb) {
            const int n = nb * 16 + lm;
            ushort4 vv = *(const ushort4*)&Xs[n * PITCH + cb];
            float x0 = bf2f(vv.x) - (acc[o][nb][0] + b2v.x);
            float x1 = bf2f(vv.y) - (acc[o][nb][1] + b2v.y);
            float x2 = bf2f(vv.z) - (acc[o][nb][2] + b2v.z);
            float x3 = bf2f(vv.w) - (acc[o][nb][3] + b2v.w);
            xr[o][nb][0] = x0; xr[o][nb][1] = x1;
            xr[o][nb][2] = x2; xr[o][nb][3] = x3;
            ushort4 q;
            q.x = f2bf(x0 * x0); q.y = f2bf(x1 * x1);
            q.z = f2bf(x2 * x2); q.w = f2bf(x3 * x3);
            *(ushort4*)&Xs[n * PITCH + cb] = q;
        }
    }
    __syncthreads();

    #pragma unroll
    for (int o = 0; o < 3; ++o)
        #pragma unroll
        for (int nb = 0; nb < 4; ++nb)
            acc[o][nb] = (f32x4){0.f, 0.f, 0.f, 0.f};

    #pragma unroll
    for (int kb = 0; kb < KB; ++kb) {
        bf16x8 bfr[4];
        #pragma unroll
        for (int nb = 0; nb < 4; ++nb)
            bfr[nb] = ldsfrag(Xs, nb * 16 + lm, kb * 32 + 8 * lh);
        #pragma unroll
        for (int o = 0; o < 3; ++o) {
            bf16x8 afr = *(const bf16x8*)(g1sw + (((3 * wave + o) * KB + kb) * 64 + lane) * 8);
            #pragma unroll
            for (int nb = 0; nb < 4; ++nb)
                acc[o][nb] = __builtin_amdgcn_mfma_f32_16x16x32_bf16(afr, bfr[nb], acc[o][nb], 0, 0, 0);
        }
    }
    __syncthreads();

    #pragma unroll
    for (int o = 0; o < 3; ++o) {
        const int cb = (3 * wave + o) * 16 + 4 * lh;
        const float4 b1v = *(const float4*)(b1r + cb);
        #pragma unroll
        for (int nb = 0; nb < 4; ++nb) {
            const int n = nb * 16 + lm;
            Of[(cb + 0) * OPITCH + n] = xr[o][nb][0] * rsq(acc[o][nb][0] + b1v.x);
            Of[(cb + 1) * OPITCH + n] = xr[o][nb][1] * rsq(acc[o][nb][1] + b1v.y);
            Of[(cb + 2) * OPITCH + n] = xr[o][nb][2] * rsq(acc[o][nb][2] + b1v.z);
            Of[(cb + 3) * OPITCH + n] = xr[o][nb][3] * rsq(acc[o][nb][3] + b1v.w);
        }
    }
    __syncthreads();

    #pragma unroll
    for (int i = 0; i < 12; ++i) {
        const int chunk = tid + 256 * i;
        const int c  = chunk >> 4;
        const int q4 = chunk & 15;
        const float* p = &Of[c * OPITCH + 4 * q4];
        float4 v;
        v.x = p[0]; v.y = p[1]; v.z = p[2]; v.w = p[3];
        *(float4*)&Yb[(size_t)c * HW + 4 * q4] = v;
    }
}

extern "C" void kernel_launch(void* const* d_in, const int* in_sizes, int n_in,
                              void* d_out, int out_size, void* d_ws, size_t ws_size,
                              hipStream_t stream) {
    const float* X      = (const float*)d_in[0];
    const float* beta   = (const float*)d_in[1];
    const float* gamma  = (const float*)d_in[2];
    const float* beta2  = (const float*)d_in[3];
    const float* gamma2 = (const float*)d_in[4];
    float* Y = (float*)d_out;

    char* ws = (char*)d_ws;
    float4*   cp   = (float4*)(ws + 0);          // 3072 B
    float*    b2r  = (float*)(ws + 3072);        // 768
    float*    b1r  = (float*)(ws + 3840);        // 768
    unsigned* flag = (unsigned*)(ws + 4608);     // 4 (+pad)
    ushort*   g2sw = (ushort*)(ws + 4624);       // 73728
    ushort*   g1sw = (ushort*)(ws + 78352);      // 73728

    hipLaunchKernelGGL(gsdn_flag0, dim3(1), dim3(1), 0, stream, flag);
    hipLaunchKernelGGL(gsdn_prep, dim3((12 * KB * 64 + 255) / 256), dim3(256), 0, stream,
                       beta, gamma, beta2, gamma2, g2sw, g1sw, b2r, b1r, cp, flag);
    hipLaunchKernelGGL(gsdn_main, dim3(HW / PN, 4), dim3(256), 0, stream,
                       X, g2sw, g1sw, b2r, b1r, cp, flag, Y);
}

// Round 9
// 73.878 us; speedup vs baseline: 1.2937x; 1.2937x over previous
//
#include <hip/hip_runtime.h>
#include <cstdint>

#define CH 192
#define HW 65536
#define PN 64           // dense path: pixels per tile
#define PITCH 196       // dense path: X-tile LDS row pitch (bf16 elems)
#define OPITCH 66       // dense path: out-tile LDS row pitch (fp32 elems)
#define KB 6            // K blocks (192/32)
#define SMEM_BYTES 50688

#define GAMMA_BOUND 3.814697265625e-06f            // 2^-18
#define PEDESTAL    1.4551915228366852e-11f        // 2^-36
#define BETA_BOUND  1.0000072759550125e-03f        // sqrt(1e-6 + 2^-36)

typedef __attribute__((ext_vector_type(8))) __bf16 bf16x8;
typedef __attribute__((ext_vector_type(4))) __bf16 bf16x4;
typedef __attribute__((ext_vector_type(4))) float  f32x4;

__device__ __forceinline__ ushort f2bf(float f) {
    __bf16 h = (__bf16)f;
    return __builtin_bit_cast(ushort, h);
}
__device__ __forceinline__ float bf2f(ushort h) {
    union { uint32_t u; float f; } v; v.u = ((uint32_t)h) << 16;
    return v.f;
}
__device__ __forceinline__ float rsq(float x) {
    float r; asm("v_rsq_f32 %0, %1" : "=v"(r) : "v"(x)); return r;
}

// ---- kernel 0: zero the structure flag (ws not re-poisoned between replays) ----
__global__ void gsdn_flag0(unsigned* flag) { *flag = 0u; }

// ---- prep: reparam params; G2/G1 -> MFMA A-frag order (dense path);
//      diagonal + bias table (diag path); off-diagonal detection -> flag ----
__global__ __launch_bounds__(256) void gsdn_prep(
    const float* __restrict__ beta, const float* __restrict__ gamma,
    const float* __restrict__ beta2, const float* __restrict__ gamma2,
    ushort* __restrict__ g2sw, ushort* __restrict__ g1sw,
    float* __restrict__ b2r, float* __restrict__ b1r,
    float4* __restrict__ cp, unsigned* __restrict__ flag)
{
    int t = blockIdx.x * 256 + threadIdx.x;
    if (t < 12 * KB * 64) {
        const int o    = t / (KB * 64);
        const int r    = t - o * (KB * 64);
        const int kb   = r >> 6;
        const int lane = r & 63;
        const int row  = o * 16 + (lane & 15);
        const int col0 = kb * 32 + 8 * (lane >> 4);
        ushort w2[8], w1[8];
        bool nz = false;
        #pragma unroll
        for (int j = 0; j < 8; ++j) {
            float g = fmaxf(gamma2[row * CH + col0 + j], GAMMA_BOUND);
            float g2v = g * g - PEDESTAL;
            w2[j] = f2bf(g2v);
            float h = fmaxf(gamma[row * CH + col0 + j], GAMMA_BOUND);
            float g1v = h * h - PEDESTAL;
            w1[j] = f2bf(g1v);
            if (row != (col0 + j) && (g2v != 0.0f || g1v != 0.0f)) nz = true;
        }
        #pragma unroll
        for (int j = 0; j < 8; ++j) { g2sw[t * 8 + j] = w2[j]; g1sw[t * 8 + j] = w1[j]; }
        if (nz) atomicOr(flag, 1u);
    }
    if (t < CH) {
        float b = fmaxf(beta2[t], BETA_BOUND);
        float b2 = b * b - PEDESTAL;
        float a = fmaxf(beta[t], BETA_BOUND);
        float b1 = a * a - PEDESTAL;
        b2r[t] = b2;
        b1r[t] = b1;
        float gd = fmaxf(gamma2[t * CH + t], GAMMA_BOUND);
        float d2 = gd * gd - PEDESTAL;
        float hd = fmaxf(gamma[t * CH + t], GAMMA_BOUND);
        float d1 = hd * hd - PEDESTAL;
        float4 p;
        p.x = 1.0f - d2;   // x = p.x*v - b2
        p.y = b2;
        p.z = d1;          // out = x*rsqrt(d1*x^2 + b1)
        p.w = b1;
        cp[t] = p;
    }
}

// ---- diagonal fast path: pure elementwise fp32, memory-bound; runs iff flag==0 ----
// grid: 4 img * 192 ch * 4 quarter-planes = 3072 blocks; 1KB/wave coalesced; nt stores.
__global__ __launch_bounds__(256) void gsdn_diag(
    const float* __restrict__ X, const float4* __restrict__ cp,
    const unsigned* __restrict__ flag, float* __restrict__ Y)
{
    if (*flag != 0u) return;
    const int b  = blockIdx.x;
    const int im = b / 768;
    const int r  = b - im * 768;
    const int c  = r >> 2;
    const int q  = r & 3;
    const float4 p = cp[c];
    const size_t base = ((size_t)im * CH + c) * (HW / 4) + (size_t)q * 4096 + threadIdx.x;
    const f32x4* xp = (const f32x4*)X + base;
    f32x4*       yp = (f32x4*)Y + base;
    #pragma unroll
    for (int k = 0; k < 16; ++k) {
        f32x4 v = xp[k * 256];
        float x0 = p.x * v[0] - p.y;
        float x1 = p.x * v[1] - p.y;
        float x2 = p.x * v[2] - p.y;
        float x3 = p.x * v[3] - p.y;
        f32x4 o;
        o[0] = x0 * rsq(p.z * x0 * x0 + p.w);
        o[1] = x1 * rsq(p.z * x1 * x1 + p.w);
        o[2] = x2 * rsq(p.z * x2 * x2 + p.w);
        o[3] = x3 * rsq(p.z * x3 * x3 + p.w);
        __builtin_nontemporal_store(o, &yp[k * 256]);
    }
}

__device__ __forceinline__ bf16x8 ldsfrag(const ushort* S, int n, int k0) {
    union { bf16x8 v; struct { bf16x4 lo; bf16x4 hi; } s; } u;
    u.s.lo = *(const bf16x4*)&S[n * PITCH + k0];
    u.s.hi = *(const bf16x4*)&S[n * PITCH + k0 + 4];
    return u.v;
}

// ---- dense fallback (r5-verified MFMA kernel), 4 tiles per WG; runs iff flag!=0 ----
__global__ __launch_bounds__(256, 3) void gsdn_main(
    const float* __restrict__ X,
    const ushort* __restrict__ g2sw, const ushort* __restrict__ g1sw,
    const float* __restrict__ b2r, const float* __restrict__ b1r,
    const unsigned* __restrict__ flag, float* __restrict__ Y)
{
    if (*flag == 0u) return;
    __shared__ char smem_raw[SMEM_BYTES];
    ushort* Xs = (ushort*)smem_raw;
    float*  Of = (float*)smem_raw;

    const int tid  = threadIdx.x;
    const int wave = tid >> 6;
    const int lane = tid & 63;
    const int lm   = lane & 15;
    const int lh   = lane >> 4;

    for (int ti = 0; ti < 4; ++ti) {
        const int base = (blockIdx.x * 4 + ti) * PN;
        const float* Xb = X + (size_t)blockIdx.y * CH * HW + base;
        float*       Yb = Y + (size_t)blockIdx.y * CH * HW + base;

        {
            const int g  = tid & 15;
            const int c0 = tid >> 4;
            #pragma unroll
            for (int j = 0; j < 12; ++j) {
                const int c = c0 + 16 * j;
                const float4 v = *(const float4*)&Xb[(size_t)c * HW + 4 * g];
                Xs[(4 * g + 0) * PITCH + c] = f2bf(v.x);
                Xs[(4 * g + 1) * PITCH + c] = f2bf(v.y);
                Xs[(4 * g + 2) * PITCH + c] = f2bf(v.z);
                Xs[(4 * g + 3) * PITCH + c] = f2bf(v.w);
            }
        }
        __syncthreads();

        f32x4 acc[3][4];
        #pragma unroll
        for (int o = 0; o < 3; ++o)
            #pragma unroll
            for (int nb = 0; nb < 4; ++nb)
                acc[o][nb] = (f32x4){0.f, 0.f, 0.f, 0.f};

        #pragma unroll
        for (int kb = 0; kb < KB; ++kb) {
            bf16x8 bfr[4];
            #pragma unroll
            for (int nb = 0; nb < 4; ++nb)
                bfr[nb] = ldsfrag(Xs, nb * 16 + lm, kb * 32 + 8 * lh);
            #pragma unroll
            for (int o = 0; o < 3; ++o) {
                bf16x8 afr = *(const bf16x8*)(g2sw + (((3 * wave + o) * KB + kb) * 64 + lane) * 8);
                #pragma unroll
                for (int nb = 0; nb < 4; ++nb)
                    acc[o][nb] = __builtin_amdgcn_mfma_f32_16x16x32_bf16(afr, bfr[nb], acc[o][nb], 0, 0, 0);
            }
        }
        __syncthreads();

        f32x4 xr[3][4];
        #pragma unroll
        for (int o = 0; o < 3; ++o) {
            const int cb = (3 * wave + o) * 16 + 4 * lh;
            const float4 b2v = *(const float4*)(b2r + cb);
            #pragma unroll
            for (int nb = 0; nb < 4; ++nb) {
                const int n = nb * 16 + lm;
                ushort4 vv = *(const ushort4*)&Xs[n * PITCH + cb];
                float x0 = bf2f(vv.x) - (acc[o][nb][0] + b2v.x);
                float x1 = bf2f(vv.y) - (acc[o][nb][1] + b2v.y);
                float x2 = bf2f(vv.z) - (acc[o][nb][2] + b2v.z);
                float x3 = bf2f(vv.w) - (acc[o][nb][3] + b2v.w);
                xr[o][nb][0] = x0; xr[o][nb][1] = x1;
                xr[o][nb][2] = x2; xr[o][nb][3] = x3;
                ushort4 q;
                q.x = f2bf(x0 * x0); q.y = f2bf(x1 * x1);
                q.z = f2bf(x2 * x2); q.w = f2bf(x3 * x3);
                *(ushort4*)&Xs[n * PITCH + cb] = q;
            }
        }
        __syncthreads();

        #pragma unroll
        for (int o = 0; o < 3; ++o)
            #pragma unroll
            for (int nb = 0; nb < 4; ++nb)
                acc[o][nb] = (f32x4){0.f, 0.f, 0.f, 0.f};

        #pragma unroll
        for (int kb = 0; kb < KB; ++kb) {
            bf16x8 bfr[4];
            #pragma unroll
            for (int nb = 0; nb < 4; ++nb)
                bfr[nb] = ldsfrag(Xs, nb * 16 + lm, kb * 32 + 8 * lh);
            #pragma unroll
            for (int o = 0; o < 3; ++o) {
                bf16x8 afr = *(const bf16x8*)(g1sw + (((3 * wave + o) * KB + kb) * 64 + lane) * 8);
                #pragma unroll
                for (int nb = 0; nb < 4; ++nb)
                    acc[o][nb] = __builtin_amdgcn_mfma_f32_16x16x32_bf16(afr, bfr[nb], acc[o][nb], 0, 0, 0);
            }
        }
        __syncthreads();

        #pragma unroll
        for (int o = 0; o < 3; ++o) {
            const int cb = (3 * wave + o) * 16 + 4 * lh;
            const float4 b1v = *(const float4*)(b1r + cb);
            #pragma unroll
            for (int nb = 0; nb < 4; ++nb) {
                const int n = nb * 16 + lm;
                Of[(cb + 0) * OPITCH + n] = xr[o][nb][0] * rsq(acc[o][nb][0] + b1v.x);
                Of[(cb + 1) * OPITCH + n] = xr[o][nb][1] * rsq(acc[o][nb][1] + b1v.y);
                Of[(cb + 2) * OPITCH + n] = xr[o][nb][2] * rsq(acc[o][nb][2] + b1v.z);
                Of[(cb + 3) * OPITCH + n] = xr[o][nb][3] * rsq(acc[o][nb][3] + b1v.w);
            }
        }
        __syncthreads();

        #pragma unroll
        for (int i = 0; i < 12; ++i) {
            const int chunk = tid + 256 * i;
            const int c  = chunk >> 4;
            const int q4 = chunk & 15;
            const float* p = &Of[c * OPITCH + 4 * q4];
            float4 v;
            v.x = p[0]; v.y = p[1]; v.z = p[2]; v.w = p[3];
            *(float4*)&Yb[(size_t)c * HW + 4 * q4] = v;
        }
        __syncthreads();   // Of reads done before next tile restages Xs
    }
}

extern "C" void kernel_launch(void* const* d_in, const int* in_sizes, int n_in,
                              void* d_out, int out_size, void* d_ws, size_t ws_size,
                              hipStream_t stream) {
    const float* X      = (const float*)d_in[0];
    const float* beta   = (const float*)d_in[1];
    const float* gamma  = (const float*)d_in[2];
    const float* beta2  = (const float*)d_in[3];
    const float* gamma2 = (const float*)d_in[4];
    float* Y = (float*)d_out;

    char* ws = (char*)d_ws;
    float4*   cp   = (float4*)(ws + 0);          // 3072 B
    float*    b2r  = (float*)(ws + 3072);        // 768
    float*    b1r  = (float*)(ws + 3840);        // 768
    unsigned* flag = (unsigned*)(ws + 4608);     // 4 (+pad)
    ushort*   g2sw = (ushort*)(ws + 4624);       // 73728
    ushort*   g1sw = (ushort*)(ws + 78352);      // 73728

    hipLaunchKernelGGL(gsdn_flag0, dim3(1), dim3(1), 0, stream, flag);
    hipLaunchKernelGGL(gsdn_prep, dim3((12 * KB * 64 + 255) / 256), dim3(256), 0, stream,
                       beta, gamma, beta2, gamma2, g2sw, g1sw, b2r, b1r, cp, flag);
    hipLaunchKernelGGL(gsdn_diag, dim3(4 * CH * 4), dim3(256), 0, stream,
                       X, cp, flag, Y);
    hipLaunchKernelGGL(gsdn_main, dim3(HW / PN / 4, 4), dim3(256), 0, stream,
                       X, g2sw, g1sw, b2r, b1r, flag, Y);
}

// Round 10
// 73.786 us; speedup vs baseline: 1.2953x; 1.0013x over previous
//
#include <hip/hip_runtime.h>
#include <cstdint>

#define CH 192
#define HW 65536
#define PN 64           // dense path: pixels per tile
#define PITCH 196       // dense path: X-tile LDS row pitch (bf16 elems)
#define OPITCH 66       // dense path: out-tile LDS row pitch (fp32 elems)
#define KB 6            // K blocks (192/32)
#define SMEM_BYTES 50688

#define GAMMA_BOUND 3.814697265625e-06f            // 2^-18
#define PEDESTAL    1.4551915228366852e-11f        // 2^-36
#define BETA_BOUND  1.0000072759550125e-03f        // sqrt(1e-6 + 2^-36)

typedef __attribute__((ext_vector_type(8))) __bf16 bf16x8;
typedef __attribute__((ext_vector_type(4))) __bf16 bf16x4;
typedef __attribute__((ext_vector_type(4))) float  f32x4;

__device__ __forceinline__ ushort f2bf(float f) {
    __bf16 h = (__bf16)f;
    return __builtin_bit_cast(ushort, h);
}
__device__ __forceinline__ float bf2f(ushort h) {
    union { uint32_t u; float f; } v; v.u = ((uint32_t)h) << 16;
    return v.f;
}
__device__ __forceinline__ float rsq(float x) {
    float r; asm("v_rsq_f32 %0, %1" : "=v"(r) : "v"(x)); return r;
}

// ---- prep: reparam params; G2/G1 -> MFMA A-frag order (dense path);
//      diagonal + bias table (diag path); off-diagonal detection -> flag ----
__global__ __launch_bounds__(256) void gsdn_prep(
    const float* __restrict__ beta, const float* __restrict__ gamma,
    const float* __restrict__ beta2, const float* __restrict__ gamma2,
    ushort* __restrict__ g2sw, ushort* __restrict__ g1sw,
    float* __restrict__ b2r, float* __restrict__ b1r,
    float4* __restrict__ cp, unsigned* __restrict__ flag)
{
    int t = blockIdx.x * 256 + threadIdx.x;
    if (t < 12 * KB * 64) {
        const int o    = t / (KB * 64);
        const int r    = t - o * (KB * 64);
        const int kb   = r >> 6;
        const int lane = r & 63;
        const int row  = o * 16 + (lane & 15);
        const int col0 = kb * 32 + 8 * (lane >> 4);
        ushort w2[8], w1[8];
        bool nz = false;
        #pragma unroll
        for (int j = 0; j < 8; ++j) {
            float g = fmaxf(gamma2[row * CH + col0 + j], GAMMA_BOUND);
            float g2v = g * g - PEDESTAL;
            w2[j] = f2bf(g2v);
            float h = fmaxf(gamma[row * CH + col0 + j], GAMMA_BOUND);
            float g1v = h * h - PEDESTAL;
            w1[j] = f2bf(g1v);
            if (row != (col0 + j) && (g2v != 0.0f || g1v != 0.0f)) nz = true;
        }
        #pragma unroll
        for (int j = 0; j < 8; ++j) { g2sw[t * 8 + j] = w2[j]; g1sw[t * 8 + j] = w1[j]; }
        if (nz) atomicOr(flag, 1u);
    }
    if (t < CH) {
        float b = fmaxf(beta2[t], BETA_BOUND);
        float b2 = b * b - PEDESTAL;
        float a = fmaxf(beta[t], BETA_BOUND);
        float b1 = a * a - PEDESTAL;
        b2r[t] = b2;
        b1r[t] = b1;
        float gd = fmaxf(gamma2[t * CH + t], GAMMA_BOUND);
        float d2 = gd * gd - PEDESTAL;
        float hd = fmaxf(gamma[t * CH + t], GAMMA_BOUND);
        float d1 = hd * hd - PEDESTAL;
        float4 p;
        p.x = 1.0f - d2;   // x = p.x*v - b2
        p.y = b2;
        p.z = d1;          // out = x*rsqrt(d1*x^2 + b1)
        p.w = b1;
        cp[t] = p;
    }
}

// ---- diagonal fast path: pure elementwise fp32, memory-bound; runs iff flag==0 ----
// grid: 4 img * 192 ch * 4 quarter-planes = 3072 blocks; 1KB/wave coalesced;
// 8-deep load batching; nt stores (no re-read -> skip L2/L3 write allocate).
__global__ __launch_bounds__(256) void gsdn_diag(
    const float* __restrict__ X, const float4* __restrict__ cp,
    const unsigned* __restrict__ flag, float* __restrict__ Y)
{
    if (*flag != 0u) return;
    const int b  = blockIdx.x;
    const int im = b / 768;
    const int r  = b - im * 768;
    const int c  = r >> 2;
    const int q  = r & 3;
    const float4 p = cp[c];
    const size_t base = ((size_t)im * CH + c) * (HW / 4) + (size_t)q * 4096 + threadIdx.x;
    const f32x4* xp = (const f32x4*)X + base;
    f32x4*       yp = (f32x4*)Y + base;
    #pragma unroll
    for (int h = 0; h < 2; ++h) {
        f32x4 v[8];
        #pragma unroll
        for (int j = 0; j < 8; ++j)
            v[j] = xp[(h * 8 + j) * 256];
        #pragma unroll
        for (int j = 0; j < 8; ++j) {
            float x0 = p.x * v[j][0] - p.y;
            float x1 = p.x * v[j][1] - p.y;
            float x2 = p.x * v[j][2] - p.y;
            float x3 = p.x * v[j][3] - p.y;
            f32x4 o;
            o[0] = x0 * rsq(p.z * x0 * x0 + p.w);
            o[1] = x1 * rsq(p.z * x1 * x1 + p.w);
            o[2] = x2 * rsq(p.z * x2 * x2 + p.w);
            o[3] = x3 * rsq(p.z * x3 * x3 + p.w);
            __builtin_nontemporal_store(o, &yp[(h * 8 + j) * 256]);
        }
    }
}

__device__ __forceinline__ bf16x8 ldsfrag(const ushort* S, int n, int k0) {
    union { bf16x8 v; struct { bf16x4 lo; bf16x4 hi; } s; } u;
    u.s.lo = *(const bf16x4*)&S[n * PITCH + k0];
    u.s.hi = *(const bf16x4*)&S[n * PITCH + k0 + 4];
    return u.v;
}

// ---- dense fallback (r5-verified MFMA kernel), 16 tiles per WG; runs iff flag!=0 ----
__global__ __launch_bounds__(256, 3) void gsdn_main(
    const float* __restrict__ X,
    const ushort* __restrict__ g2sw, const ushort* __restrict__ g1sw,
    const float* __restrict__ b2r, const float* __restrict__ b1r,
    const unsigned* __restrict__ flag, float* __restrict__ Y)
{
    if (*flag == 0u) return;
    __shared__ char smem_raw[SMEM_BYTES];
    ushort* Xs = (ushort*)smem_raw;
    float*  Of = (float*)smem_raw;

    const int tid  = threadIdx.x;
    const int wave = tid >> 6;
    const int lane = tid & 63;
    const int lm   = lane & 15;
    const int lh   = lane >> 4;

    for (int ti = 0; ti < 16; ++ti) {
        const int base = (blockIdx.x * 16 + ti) * PN;
        const float* Xb = X + (size_t)blockIdx.y * CH * HW + base;
        float*       Yb = Y + (size_t)blockIdx.y * CH * HW + base;

        {
            const int g  = tid & 15;
            const int c0 = tid >> 4;
            #pragma unroll
            for (int j = 0; j < 12; ++j) {
                const int c = c0 + 16 * j;
                const float4 v = *(const float4*)&Xb[(size_t)c * HW + 4 * g];
                Xs[(4 * g + 0) * PITCH + c] = f2bf(v.x);
                Xs[(4 * g + 1) * PITCH + c] = f2bf(v.y);
                Xs[(4 * g + 2) * PITCH + c] = f2bf(v.z);
                Xs[(4 * g + 3) * PITCH + c] = f2bf(v.w);
            }
        }
        __syncthreads();

        f32x4 acc[3][4];
        #pragma unroll
        for (int o = 0; o < 3; ++o)
            #pragma unroll
            for (int nb = 0; nb < 4; ++nb)
                acc[o][nb] = (f32x4){0.f, 0.f, 0.f, 0.f};

        #pragma unroll
        for (int kb = 0; kb < KB; ++kb) {
            bf16x8 bfr[4];
            #pragma unroll
            for (int nb = 0; nb < 4; ++nb)
                bfr[nb] = ldsfrag(Xs, nb * 16 + lm, kb * 32 + 8 * lh);
            #pragma unroll
            for (int o = 0; o < 3; ++o) {
                bf16x8 afr = *(const bf16x8*)(g2sw + (((3 * wave + o) * KB + kb) * 64 + lane) * 8);
                #pragma unroll
                for (int nb = 0; nb < 4; ++nb)
                    acc[o][nb] = __builtin_amdgcn_mfma_f32_16x16x32_bf16(afr, bfr[nb], acc[o][nb], 0, 0, 0);
            }
        }
        __syncthreads();

        f32x4 xr[3][4];
        #pragma unroll
        for (int o = 0; o < 3; ++o) {
            const int cb = (3 * wave + o) * 16 + 4 * lh;
            const float4 b2v = *(const float4*)(b2r + cb);
            #pragma unroll
            for (int nb = 0; nb < 4; ++nb) {
                const int n = nb * 16 + lm;
                ushort4 vv = *(const ushort4*)&Xs[n * PITCH + cb];
                float x0 = bf2f(vv.x) - (acc[o][nb][0] + b2v.x);
                float x1 = bf2f(vv.y) - (acc[o][nb][1] + b2v.y);
                float x2 = bf2f(vv.z) - (acc[o][nb][2] + b2v.z);
                float x3 = bf2f(vv.w) - (acc[o][nb][3] + b2v.w);
                xr[o][nb][0] = x0; xr[o][nb][1] = x1;
                xr[o][nb][2] = x2; xr[o][nb][3] = x3;
                ushort4 q;
                q.x = f2bf(x0 * x0); q.y = f2bf(x1 * x1);
                q.z = f2bf(x2 * x2); q.w = f2bf(x3 * x3);
                *(ushort4*)&Xs[n * PITCH + cb] = q;
            }
        }
        __syncthreads();

        #pragma unroll
        for (int o = 0; o < 3; ++o)
            #pragma unroll
            for (int nb = 0; nb < 4; ++nb)
                acc[o][nb] = (f32x4){0.f, 0.f, 0.f, 0.f};

        #pragma unroll
        for (int kb = 0; kb < KB; ++kb) {
            bf16x8 bfr[4];
            #pragma unroll
            for (int nb = 0; nb < 4; ++nb)
                bfr[nb] = ldsfrag(Xs, nb * 16 + lm, kb * 32 + 8 * lh);
            #pragma unroll
            for (int o = 0; o < 3; ++o) {
                bf16x8 afr = *(const bf16x8*)(g1sw + (((3 * wave + o) * KB + kb) * 64 + lane) * 8);
                #pragma unroll
                for (int nb = 0; nb < 4; ++nb)
                    acc[o][nb] = __builtin_amdgcn_mfma_f32_16x16x32_bf16(afr, bfr[nb], acc[o][nb], 0, 0, 0);
            }
        }
        __syncthreads();

        #pragma unroll
        for (int o = 0; o < 3; ++o) {
            const int cb = (3 * wave + o) * 16 + 4 * lh;
            const float4 b1v = *(const float4*)(b1r + cb);
            #pragma unroll
            for (int nb = 0; nb < 4; ++nb) {
                const int n = nb * 16 + lm;
                Of[(cb + 0) * OPITCH + n] = xr[o][nb][0] * rsq(acc[o][nb][0] + b1v.x);
                Of[(cb + 1) * OPITCH + n] = xr[o][nb][1] * rsq(acc[o][nb][1] + b1v.y);
                Of[(cb + 2) * OPITCH + n] = xr[o][nb][2] * rsq(acc[o][nb][2] + b1v.z);
                Of[(cb + 3) * OPITCH + n] = xr[o][nb][3] * rsq(acc[o][nb][3] + b1v.w);
            }
        }
        __syncthreads();

        #pragma unroll
        for (int i = 0; i < 12; ++i) {
            const int chunk = tid + 256 * i;
            const int c  = chunk >> 4;
            const int q4 = chunk & 15;
            const float* p = &Of[c * OPITCH + 4 * q4];
            float4 v;
            v.x = p[0]; v.y = p[1]; v.z = p[2]; v.w = p[3];
            *(float4*)&Yb[(size_t)c * HW + 4 * q4] = v;
        }
        __syncthreads();   // Of reads done before next tile restages Xs
    }
}

extern "C" void kernel_launch(void* const* d_in, const int* in_sizes, int n_in,
                              void* d_out, int out_size, void* d_ws, size_t ws_size,
                              hipStream_t stream) {
    const float* X      = (const float*)d_in[0];
    const float* beta   = (const float*)d_in[1];
    const float* gamma  = (const float*)d_in[2];
    const float* beta2  = (const float*)d_in[3];
    const float* gamma2 = (const float*)d_in[4];
    float* Y = (float*)d_out;

    char* ws = (char*)d_ws;
    float4*   cp   = (float4*)(ws + 0);          // 3072 B
    float*    b2r  = (float*)(ws + 3072);        // 768
    float*    b1r  = (float*)(ws + 3840);        // 768
    unsigned* flag = (unsigned*)(ws + 4608);     // 4 (+pad)
    ushort*   g2sw = (ushort*)(ws + 4624);       // 73728
    ushort*   g1sw = (ushort*)(ws + 78352);      // 73728

    hipMemsetAsync(flag, 0, 4, stream);          // memset node (capture-legal)
    hipLaunchKernelGGL(gsdn_prep, dim3((12 * KB * 64 + 255) / 256), dim3(256), 0, stream,
                       beta, gamma, beta2, gamma2, g2sw, g1sw, b2r, b1r, cp, flag);
    hipLaunchKernelGGL(gsdn_diag, dim3(4 * CH * 4), dim3(256), 0, stream,
                       X, cp, flag, Y);
    hipLaunchKernelGGL(gsdn_main, dim3(HW / PN / 16, 4), dim3(256), 0, stream,
                       X, g2sw, g1sw, b2r, b1r, flag, Y);
}